// Round 3
// baseline (1017.585 us; speedup 1.0000x reference)
//
#include <hip/hip_runtime.h>
#include <hip/hip_bf16.h>
#include <stdint.h>
#include <math.h>

#define DM 1024
#define DH 2048
#define NB 4
#define SL 4096
#define MT (NB*SL)   // 16384 rows
#define LC 256       // scan chunk length
#define NC (SL/LC)   // 16 chunks per channel

typedef __bf16 bf16;
typedef __attribute__((ext_vector_type(8))) __bf16 bf16x8;
typedef __attribute__((ext_vector_type(4))) __bf16 bf16x4;
typedef __attribute__((ext_vector_type(4))) float f32x4;

// ===========================================================================
// Fused fp32 -> bf16 sanitizing convert for all 9 tensors in one launch
// (NaN -> 0, clamp +-65504), vectorized x4. Segment table in kernel args.
// ===========================================================================
struct CvtArgs {
  const float* in[9];
  bf16* out[9];
  int cum[10];   // cumulative vec4 counts, cum[0]=0
};

__global__ void cvt_all(CvtArgs a) {
  const int total4 = a.cum[9];
  for (int i = blockIdx.x * 256 + threadIdx.x; i < total4; i += gridDim.x * 256) {
    int s = 0;
#pragma unroll 8
    while (i >= a.cum[s + 1]) ++s;        // contiguous i => wave-uniform mostly
    const int j = i - a.cum[s];
    f32x4 v = *(const f32x4*)(a.in[s] + 4 * (size_t)j);
    bf16x4 o;
#pragma unroll
    for (int k = 0; k < 4; ++k) {
      float x = v[k];
      x = (x == x) ? fminf(fmaxf(x, -65504.f), 65504.f) : 0.f;
      o[k] = (bf16)x;
    }
    *(bf16x4*)(a.out[s] + 4 * (size_t)j) = o;
  }
}

// ===========================================================================
// Round-3 changes (round-2 PMC: gemm_dual 142us, MfmaUtil 43, VALUBusy 33,
// Occupancy 21% = 2 blocks/CU -- LDS 68KB was the binding limit; the
// per-K-step vmcnt(0)+barrier drain is only hidden by cross-block overlap):
//  1. gemm_dual epilogue restages acc1 then acc2 sequentially through ONE
//     wave-private 32x68 slot (acc1 read-back parked in 32 VGPRs; same-wave
//     DS ops are program-ordered). LDS 69632 -> 49152 => 3 blocks/CU.
//  2. 9 cvt launches fused into 1 (cvt_all).
// Everything else kept from round 2 (global_load_lds staging, XOR-swizzled
// LDS with pre-swizzled global source, LDS-restage coalesced epilogue,
// MODE5+6 dual fusion, concat-K C/D fusion, XCD swizzle).
// MODE 0: out_bf16 = acc (+bias1 (+bias2 if K2))
// MODE 1: out_f32  = acc + extra_bf16[off]          (final residual)
// MODE 2: out_bf16 = extra_bf16[off] * silu(acc)    (z-gate)
// ===========================================================================

__device__ __forceinline__ void g2lds(const bf16* g, bf16* l) {
  __builtin_amdgcn_global_load_lds((const __attribute__((address_space(1))) void*)g,
                                   (__attribute__((address_space(3))) void*)l,
                                   16, 0, 0);
}

// One K-pass: stages [128 rows x 64 k] of A and W via global_load_lds and
// accumulates into acc. 2 barriers per K-step (m97 structure).
template<int KK>
__device__ __forceinline__ void gemm_pass(const bf16* __restrict__ Abase,
                                          const bf16* __restrict__ Wbase,
                                          bf16* lds_a, bf16* lds_b,
                                          f32x4 (&acc)[4][4],
                                          int wave, int lane,
                                          size_t arow0, size_t brow0) {
  const int wm = wave >> 1, wn = wave & 1;
  const int r_in = lane >> 3;
  const int kc_l = (lane & 7) ^ r_in;     // pre-swizzled global k-chunk
  const int mrow = lane & 15;
  const int kg   = lane >> 4;

  const bf16* pa[4];
  const bf16* pb[4];
#pragma unroll
  for (int iss = 0; iss < 4; ++iss) {
    const int row = (iss * 4 + wave) * 8 + r_in;
    pa[iss] = Abase + (arow0 + row) * (size_t)KK + kc_l * 8;
    pb[iss] = Wbase + (brow0 + row) * (size_t)KK + kc_l * 8;
  }

#pragma unroll 1
  for (int k0 = 0; k0 < KK; k0 += 64) {
    __syncthreads();                      // prev tile's readers done
#pragma unroll
    for (int iss = 0; iss < 4; ++iss) {
      const int chunk = iss * 4 + wave;   // wave-uniform LDS base; lane*16 implicit
      g2lds(pa[iss], &lds_a[chunk * 512]); pa[iss] += 64;
      g2lds(pb[iss], &lds_b[chunk * 512]); pb[iss] += 64;
    }
    __syncthreads();                      // vmcnt(0) drain => tile valid
#pragma unroll
    for (int ks = 0; ks < 2; ++ks) {
      bf16x8 af[4], bfr[4];
#pragma unroll
      for (int t = 0; t < 4; ++t) {
        const int ra = wm * 64 + t * 16 + mrow;
        const int sa = ra * 8 + ((ks * 4 + kg) ^ (ra & 7));
        af[t] = *(const bf16x8*)&lds_a[sa * 8];
        const int rb = wn * 64 + t * 16 + mrow;
        const int sb = rb * 8 + ((ks * 4 + kg) ^ (rb & 7));
        bfr[t] = *(const bf16x8*)&lds_b[sb * 8];
      }
#pragma unroll
      for (int i = 0; i < 4; ++i)
#pragma unroll
        for (int j = 0; j < 4; ++j)
          acc[i][j] = __builtin_amdgcn_mfma_f32_16x16x32_bf16(af[i], bfr[j], acc[i][j], 0, 0, 0);
    }
  }
}

template<int MODE, bool HAS_BIAS, int N, int K1, int K2>
__global__ __launch_bounds__(256, 3)
void gemm_bt(const bf16* __restrict__ A1, const bf16* __restrict__ W1,
             const float* __restrict__ bias1,
             const bf16* __restrict__ A2, const bf16* __restrict__ W2,
             const float* __restrict__ bias2,
             const void* __restrict__ extra, void* __restrict__ outp) {
  // K-loop uses [0,32768); epilogue reuses pool as 4 per-wave 32x68 f32 slots.
  __shared__ __align__(16) char pool[34816];
  bf16* lds_a = (bf16*)pool;
  bf16* lds_b = (bf16*)(pool + 16384);

  const int tid  = threadIdx.x;
  const int wave = tid >> 6;
  const int lane = tid & 63;
  const int wm = wave >> 1, wn = wave & 1;

  // XCD-aware swizzle (bijective: gridDim.y % 8 == 0).
  constexpr int NBN = N / 128;
  const int nbm8 = (int)(gridDim.y >> 3);
  const int id   = (int)(blockIdx.y * NBN + blockIdx.x);
  const int xcd  = id & 7;
  const unsigned jj = (unsigned)id >> 3;
  const int bm   = xcd * nbm8 + (int)(jj / (unsigned)NBN);
  const int bn   = (int)(jj & (NBN - 1));
  const size_t arow0 = (size_t)bm * 128;
  const size_t brow0 = (size_t)bn * 128;

  f32x4 acc[4][4];
#pragma unroll
  for (int i = 0; i < 4; ++i)
#pragma unroll
    for (int j = 0; j < 4; ++j) acc[i][j] = {0.f, 0.f, 0.f, 0.f};

  gemm_pass<K1>(A1, W1, lds_a, lds_b, acc, wave, lane, arow0, brow0);
  if constexpr (K2 > 0)
    gemm_pass<K2>(A2, W2, lds_a, lds_b, acc, wave, lane, arow0, brow0);

  const int mrow = lane & 15;
  const int kg   = lane >> 4;

  // Epilogue: LDS restage -> coalesced stores (see round-1 notes).
  __syncthreads();
  float* eps = (float*)pool + wave * 2176; // 32*68 floats per wave
  const int rr  = lane >> 3;
  const int cc  = (lane & 7) * 8;
  const int gcol0 = bn * 128 + wn * 64 + cc;
  f32x4 bv0 = {0.f, 0.f, 0.f, 0.f}, bv1 = {0.f, 0.f, 0.f, 0.f};
  if constexpr (HAS_BIAS) {
    bv0 = *(const f32x4*)(bias1 + gcol0);
    bv1 = *(const f32x4*)(bias1 + gcol0 + 4);
  }
  if constexpr (K2 > 0) {
    bv0 += *(const f32x4*)(bias2 + gcol0);
    bv1 += *(const f32x4*)(bias2 + gcol0 + 4);
  }

#pragma unroll
  for (int p = 0; p < 2; ++p) {
#pragma unroll
    for (int ii = 0; ii < 2; ++ii) {
      const int i = p * 2 + ii;
#pragma unroll
      for (int j = 0; j < 4; ++j)
#pragma unroll
        for (int r = 0; r < 4; ++r)
          eps[(ii * 16 + kg * 4 + r) * 68 + j * 16 + mrow] = acc[i][j][r];
    }
#pragma unroll
    for (int rnd = 0; rnd < 4; ++rnd) {
      const int lr   = rnd * 8 + rr;
      const int grow = bm * 128 + wm * 64 + p * 32 + lr;
      f32x4 v0 = *(const f32x4*)&eps[lr * 68 + cc];
      f32x4 v1 = *(const f32x4*)&eps[lr * 68 + cc + 4];
      const size_t off = (size_t)grow * N + gcol0;
      float vv[8];
#pragma unroll
      for (int k = 0; k < 4; ++k) { vv[k] = v0[k] + bv0[k]; vv[4 + k] = v1[k] + bv1[k]; }

      float res[8];
      if constexpr (MODE == 0) {
#pragma unroll
        for (int k = 0; k < 8; ++k) res[k] = vv[k];
      } else if constexpr (MODE == 1) {
        bf16x8 e = *(const bf16x8*)((const bf16*)extra + off);
#pragma unroll
        for (int k = 0; k < 8; ++k) res[k] = vv[k] + (float)e[k];
      } else {  // MODE 2
        bf16x8 g = *(const bf16x8*)((const bf16*)extra + off);
#pragma unroll
        for (int k = 0; k < 8; ++k) {
          const float v = vv[k];
          res[k] = (float)g[k] * (v / (1.f + __expf(-v)));
        }
      }

      if constexpr (MODE == 1) {
        f32x4 o0, o1;
#pragma unroll
        for (int k = 0; k < 4; ++k) { o0[k] = res[k]; o1[k] = res[4 + k]; }
        *(f32x4*)((float*)outp + off)     = o0;
        *(f32x4*)((float*)outp + off + 4) = o1;
      } else {
        bf16x8 o;
#pragma unroll
        for (int k = 0; k < 8; ++k) o[k] = (bf16)res[k];
        *(bf16x8*)((bf16*)outp + off) = o;
      }
    }
  }
}

// ===========================================================================
// Dual GEMM: nla = softplus(A.dlw^T + b1) * (A.Aw^T + b2). Shares the A-tile
// across two accumulators; W1/W2 each staged. N=2048, K=1024.
// LDS capped at 49152 (K-loop tiles) => 3 blocks/CU; epilogue uses ONE
// wave-private slot sequentially (acc1 parked in VGPRs while acc2 restages).
// ===========================================================================
template<int N, int K>
__global__ __launch_bounds__(256, 3)
void gemm_dual(const bf16* __restrict__ A, const bf16* __restrict__ W1,
               const bf16* __restrict__ W2, const float* __restrict__ b1,
               const float* __restrict__ b2, bf16* __restrict__ outp) {
  __shared__ __align__(16) char pool[49152];
  bf16* lds_a  = (bf16*)pool;
  bf16* lds_b1 = (bf16*)(pool + 16384);
  bf16* lds_b2 = (bf16*)(pool + 32768);

  const int tid  = threadIdx.x;
  const int wave = tid >> 6;
  const int lane = tid & 63;
  const int wm = wave >> 1, wn = wave & 1;

  constexpr int NBN = N / 128;
  const int nbm8 = (int)(gridDim.y >> 3);
  const int id   = (int)(blockIdx.y * NBN + blockIdx.x);
  const int xcd  = id & 7;
  const unsigned jj = (unsigned)id >> 3;
  const int bm   = xcd * nbm8 + (int)(jj / (unsigned)NBN);
  const int bn   = (int)(jj & (NBN - 1));
  const size_t arow0 = (size_t)bm * 128;
  const size_t brow0 = (size_t)bn * 128;

  const int r_in = lane >> 3;
  const int kc_l = (lane & 7) ^ r_in;
  const int mrow = lane & 15;
  const int kg   = lane >> 4;

  f32x4 acc1[4][4], acc2[4][4];
#pragma unroll
  for (int i = 0; i < 4; ++i)
#pragma unroll
    for (int j = 0; j < 4; ++j) { acc1[i][j] = {0.f,0.f,0.f,0.f}; acc2[i][j] = {0.f,0.f,0.f,0.f}; }

  const bf16* pa[4]; const bf16* pb1[4]; const bf16* pb2[4];
#pragma unroll
  for (int iss = 0; iss < 4; ++iss) {
    const int row = (iss * 4 + wave) * 8 + r_in;
    pa[iss]  = A  + (arow0 + row) * (size_t)K + kc_l * 8;
    pb1[iss] = W1 + (brow0 + row) * (size_t)K + kc_l * 8;
    pb2[iss] = W2 + (brow0 + row) * (size_t)K + kc_l * 8;
  }

#pragma unroll 1
  for (int k0 = 0; k0 < K; k0 += 64) {
    __syncthreads();
#pragma unroll
    for (int iss = 0; iss < 4; ++iss) {
      const int chunk = iss * 4 + wave;
      g2lds(pa[iss],  &lds_a [chunk * 512]); pa[iss]  += 64;
      g2lds(pb1[iss], &lds_b1[chunk * 512]); pb1[iss] += 64;
      g2lds(pb2[iss], &lds_b2[chunk * 512]); pb2[iss] += 64;
    }
    __syncthreads();
#pragma unroll
    for (int ks = 0; ks < 2; ++ks) {
      bf16x8 af[4], b1f[4], b2f[4];
#pragma unroll
      for (int t = 0; t < 4; ++t) {
        const int ra = wm * 64 + t * 16 + mrow;
        const int sa = ra * 8 + ((ks * 4 + kg) ^ (ra & 7));
        af[t] = *(const bf16x8*)&lds_a[sa * 8];
        const int rb = wn * 64 + t * 16 + mrow;
        const int sb = rb * 8 + ((ks * 4 + kg) ^ (rb & 7));
        b1f[t] = *(const bf16x8*)&lds_b1[sb * 8];
        b2f[t] = *(const bf16x8*)&lds_b2[sb * 8];
      }
#pragma unroll
      for (int i = 0; i < 4; ++i)
#pragma unroll
        for (int j = 0; j < 4; ++j) {
          acc1[i][j] = __builtin_amdgcn_mfma_f32_16x16x32_bf16(af[i], b1f[j], acc1[i][j], 0, 0, 0);
          acc2[i][j] = __builtin_amdgcn_mfma_f32_16x16x32_bf16(af[i], b2f[j], acc2[i][j], 0, 0, 0);
        }
    }
  }

  // Epilogue: ONE slot per wave, acc1 then acc2 (same-wave DS ops are
  // program-ordered; slot is wave-private so no barrier needed between).
  __syncthreads();
  float* eps = (float*)pool + wave * 2176;
  const int rr  = lane >> 3;
  const int cc  = (lane & 7) * 8;
  const int gcol0 = bn * 128 + wn * 64 + cc;
  f32x4 b1v0 = *(const f32x4*)(b1 + gcol0);
  f32x4 b1v1 = *(const f32x4*)(b1 + gcol0 + 4);
  f32x4 b2v0 = *(const f32x4*)(b2 + gcol0);
  f32x4 b2v1 = *(const f32x4*)(b2 + gcol0 + 4);

#pragma unroll
  for (int p = 0; p < 2; ++p) {
    // acc1 -> slot -> VGPRs
#pragma unroll
    for (int ii = 0; ii < 2; ++ii) {
      const int i = p * 2 + ii;
#pragma unroll
      for (int j = 0; j < 4; ++j)
#pragma unroll
        for (int r = 0; r < 4; ++r)
          eps[(ii * 16 + kg * 4 + r) * 68 + j * 16 + mrow] = acc1[i][j][r];
    }
    f32x4 rv0[4], rv1[4];
#pragma unroll
    for (int rnd = 0; rnd < 4; ++rnd) {
      const int lr = rnd * 8 + rr;
      rv0[rnd] = *(const f32x4*)&eps[lr * 68 + cc];
      rv1[rnd] = *(const f32x4*)&eps[lr * 68 + cc + 4];
    }
    // acc2 -> slot (overwrites; in-order per wave)
#pragma unroll
    for (int ii = 0; ii < 2; ++ii) {
      const int i = p * 2 + ii;
#pragma unroll
      for (int j = 0; j < 4; ++j)
#pragma unroll
        for (int r = 0; r < 4; ++r)
          eps[(ii * 16 + kg * 4 + r) * 68 + j * 16 + mrow] = acc2[i][j][r];
    }
#pragma unroll
    for (int rnd = 0; rnd < 4; ++rnd) {
      const int lr   = rnd * 8 + rr;
      const int grow = bm * 128 + wm * 64 + p * 32 + lr;
      f32x4 w0  = *(const f32x4*)&eps[lr * 68 + cc];
      f32x4 w1v = *(const f32x4*)&eps[lr * 68 + cc + 4];
      const size_t off = (size_t)grow * N + gcol0;
      bf16x8 o;
#pragma unroll
      for (int k = 0; k < 8; ++k) {
        const float dv = (k < 4 ? rv0[rnd][k] + b1v0[k] : rv1[rnd][k - 4] + b1v1[k - 4]);
        const float av = (k < 4 ? w0[k] + b2v0[k] : w1v[k - 4] + b2v1[k - 4]);
        const float sp = (dv > 15.f) ? dv : __logf(1.f + __expf(dv));
        o[k] = (bf16)(sp * av);
      }
      *(bf16x8*)(outp + off) = o;
    }
  }
}

// ===========================================================================
// depthwise conv1d(k=3, pad=1 along L, per-batch) + bias + silu. 8 d's/thread.
// ===========================================================================
__global__ void conv_silu_kernel(const bf16* __restrict__ t1, const float* __restrict__ cw,
                                 const float* __restrict__ cb, bf16* __restrict__ xc) {
  const int gid  = blockIdx.x * 256 + threadIdx.x;
  const int dgrp = gid & (DM / 8 - 1);
  const int bl   = gid >> 7;
  const int l    = bl & (SL - 1);
  const int d0   = dgrp * 8;
  const bf16* p  = t1 + (size_t)bl * DM + d0;
  bf16x8 cc = *(const bf16x8*)p;
  bf16x8 lf, rt;
#pragma unroll
  for (int j = 0; j < 8; ++j) { lf[j] = (bf16)0.f; rt[j] = (bf16)0.f; }
  if (l > 0)      lf = *(const bf16x8*)(p - DM);
  if (l < SL - 1) rt = *(const bf16x8*)(p + DM);
  bf16x8 o;
#pragma unroll
  for (int j = 0; j < 8; ++j) {
    const int d = d0 + j;
    float y = cw[d * 3 + 0] * (float)lf[j] + cw[d * 3 + 1] * (float)cc[j]
            + cw[d * 3 + 2] * (float)rt[j] + cb[d];
    y = y / (1.f + __expf(-y));
    o[j] = (bf16)y;
  }
  *(bf16x8*)(xc + (size_t)bl * DM + d0) = o;
}

// ===========================================================================
// Parallel scan over L, 3 phases, chunked (LC=256, NC=16).
// ===========================================================================
__global__ void scan_phase1(bf16* nla_sl, const bf16* __restrict__ bx,
                            float* __restrict__ Lp_tot, float* __restrict__ T_tot) {
  const int g  = blockIdx.x * 256 + threadIdx.x;
  const int ch = g & (DH - 1);
  const int rc = g >> 11;
  const int b  = rc & (NB - 1);
  const int c  = rc >> 2;
  const int bc = b * DH + ch;
  size_t off = ((size_t)(b * SL + c * LC)) * DH + ch;
  float lp = 0.f, S = 0.f;
#pragma unroll 8
  for (int l = 0; l < LC; ++l, off += DH) {
    const float a = (float)nla_sl[off];
    const float x = (float)bx[off];
    lp += a;
    const float e = __expf(-fminf(fmaxf(lp, -80.f), 80.f));
    S = fmaf(x, e, S);
    nla_sl[off] = (bf16)S;
  }
  Lp_tot[c * (NB * DH) + bc] = lp;
  T_tot [c * (NB * DH) + bc] = S;
}

__global__ void scan_phase2(const float* __restrict__ Lp_tot, const float* __restrict__ T_tot,
                            float* __restrict__ lpoff, float* __restrict__ Soff) {
  const int bc = blockIdx.x * 256 + threadIdx.x;
  float lp = 0.f, S = 0.f;
#pragma unroll
  for (int c = 0; c < NC; ++c) {
    lpoff[c * (NB * DH) + bc] = lp;
    Soff [c * (NB * DH) + bc] = S;
    const float e = __expf(-fminf(fmaxf(lp, -80.f), 80.f));
    S  = fmaf(e, T_tot[c * (NB * DH) + bc], S);
    lp += Lp_tot[c * (NB * DH) + bc];
  }
}

__global__ void scan_phase3(const bf16* __restrict__ S_local, bf16* __restrict__ h,
                            const float* __restrict__ lpoff, const float* __restrict__ Soff) {
  const int g  = blockIdx.x * 256 + threadIdx.x;
  const int ch = g & (DH - 1);
  const int rc = g >> 11;
  const int b  = rc & (NB - 1);
  const int c  = rc >> 2;
  const int bc = b * DH + ch;
  const float lo = lpoff[c * (NB * DH) + bc];
  const float so = Soff [c * (NB * DH) + bc];
  const float es = __expf(-fminf(fmaxf(lo, -80.f), 80.f));
  size_t off = ((size_t)(b * SL + c * LC)) * DH + ch;
#pragma unroll 8
  for (int l = 0; l < LC; ++l, off += DH) {
    h[off] = (bf16)fmaf(es, (float)S_local[off], so);
  }
}

// ===========================================================================
// Workspace (max live 186 MB), offsets in MB:
//  [  0.. 24): bf16 weights (persistent)
//  [ 24.. 56): xc
//  [ 56..120): t1 [56,88) / xbf [88,120) -> bxh (Bx, then h) ; z [56,88)
//  [120..184): nla (scan in-place) -> ssm [120,152)
//  [184..186): scan totals
// ===========================================================================
extern "C" void kernel_launch(void* const* d_in, const int* in_sizes, int n_in,
                              void* d_out, int out_size, void* d_ws, size_t ws_size,
                              hipStream_t stream) {
  const float* x    = (const float*)d_in[0];
  const float* w1   = (const float*)d_in[1];
  const float* w2   = (const float*)d_in[2];
  const float* w3   = (const float*)d_in[3];
  const float* cw   = (const float*)d_in[4];
  const float* cb   = (const float*)d_in[5];
  const float* A_w  = (const float*)d_in[6];
  const float* A_b  = (const float*)d_in[7];
  const float* B_w  = (const float*)d_in[8];
  const float* B_b  = (const float*)d_in[9];
  const float* C_w  = (const float*)d_in[10];
  const float* C_b  = (const float*)d_in[11];
  const float* D_w  = (const float*)d_in[12];
  const float* D_b  = (const float*)d_in[13];
  const float* dl_w = (const float*)d_in[14];
  const float* dl_b = (const float*)d_in[15];

  const size_t MB = 1048576u;
  char* ws = (char*)d_ws;
  bf16* w1b  = (bf16*)(ws + 0*MB);
  bf16* w2b  = (bf16*)(ws + 2*MB);
  bf16* w3b  = (bf16*)(ws + 4*MB);
  bf16* Dwb  = (bf16*)(ws + 6*MB);
  bf16* Awb  = (bf16*)(ws + 8*MB);
  bf16* Bwb  = (bf16*)(ws + 12*MB);
  bf16* dlwb = (bf16*)(ws + 16*MB);
  bf16* Cwb  = (bf16*)(ws + 20*MB);
  bf16* xc   = (bf16*)(ws + 24*MB);
  bf16* t1   = (bf16*)(ws + 56*MB);
  bf16* z    = t1;
  bf16* xbf  = (bf16*)(ws + 88*MB);
  bf16* bxh  = (bf16*)(ws + 56*MB);   // 64 MB: Bx, then h (phase3 in-place)
  bf16* nla  = (bf16*)(ws + 120*MB);  // 64 MB; S_local in-place
  bf16* ssm  = (bf16*)(ws + 120*MB);  // 32 MB, after nla dies (post-scan3)
  float* Lp_tot = (float*)(ws + 184*MB);
  float* T_tot  = (float*)(ws + 184*MB + 524288u);
  float* lpoff  = (float*)(ws + 185*MB);
  float* Soff   = (float*)(ws + 185*MB + 524288u);
  float* outp = (float*)d_out;

  dim3 blk(256);
  dim3 g1(DM / 128, MT / 128);   // N=1024
  dim3 g2(DH / 128, MT / 128);   // N=2048

  // --- convert all inputs to bf16 (sanitizing), single launch ---
  {
    CvtArgs a;
    const float* ins[9]  = {x, w1, w2, w3, D_w, A_w, B_w, dl_w, C_w};
    bf16*        outs[9] = {xbf, w1b, w2b, w3b, Dwb, Awb, Bwb, dlwb, Cwb};
    const int    n4s[9]  = {MT*DM/4, DM*DM/4, DM*DM/4, DM*DM/4, DM*DM/4,
                            DH*DM/4, DH*DM/4, DH*DM/4, DM*DH/4};
    int c = 0;
    a.cum[0] = 0;
    for (int i = 0; i < 9; ++i) { a.in[i] = ins[i]; a.out[i] = outs[i]; c += n4s[i]; a.cum[i+1] = c; }
    cvt_all<<<2048, blk, 0, stream>>>(a);
  }

  // --- pipeline ---
  gemm_bt<0,false,DM,DM,0><<<g1, blk, 0, stream>>>(xbf, w1b, nullptr,
      nullptr, nullptr, nullptr, nullptr, t1);
  conv_silu_kernel<<<MT * DM / 8 / 256, blk, 0, stream>>>(t1, cw, cb, xc);
  gemm_dual<DH,DM><<<g2, blk, 0, stream>>>(xc, dlwb, Awb, dl_b, A_b, nla);
  gemm_bt<0,true ,DH,DM,0><<<g2, blk, 0, stream>>>(xc, Bwb, B_b,
      nullptr, nullptr, nullptr, nullptr, bxh);
  scan_phase1<<<MT * NC * DH / SL / 256, blk, 0, stream>>>(nla, bxh, Lp_tot, T_tot);
  scan_phase2<<<NB * DH / 256, blk, 0, stream>>>(Lp_tot, T_tot, lpoff, Soff);
  scan_phase3<<<MT * NC * DH / SL / 256, blk, 0, stream>>>(nla, bxh, lpoff, Soff);
  // ssm = C.h + D.x + C_b + D_b  (concatenated-K fused pass)
  gemm_bt<0,true ,DM,DH,DM><<<g1, blk, 0, stream>>>(bxh, Cwb, C_b,
      xc, Dwb, D_b, nullptr, ssm);
  gemm_bt<2,false,DM,DM,0><<<g1, blk, 0, stream>>>(ssm, w2b, nullptr,
      nullptr, nullptr, nullptr, ssm, z);
  gemm_bt<1,false,DM,DM,0><<<g1, blk, 0, stream>>>(z,   w3b, nullptr,
      nullptr, nullptr, nullptr, ssm, outp);
}

// Round 4
// 642.250 us; speedup vs baseline: 1.5844x; 1.5844x over previous
//
#include <hip/hip_runtime.h>
#include <hip/hip_bf16.h>
#include <stdint.h>
#include <math.h>

#define DM 1024
#define DH 2048
#define NB 4
#define SL 4096
#define MT (NB*SL)   // 16384 rows
#define LC 256       // scan chunk length
#define NC (SL/LC)   // 16 chunks per channel

typedef __bf16 bf16;
typedef __attribute__((ext_vector_type(8))) __bf16 bf16x8;
typedef __attribute__((ext_vector_type(4))) __bf16 bf16x4;
typedef __attribute__((ext_vector_type(4))) float f32x4;

// ===========================================================================
// Fused fp32 -> bf16 sanitizing convert for all 9 tensors in one launch
// (NaN -> 0, clamp +-65504), vectorized x4. Segment table in kernel args.
// ===========================================================================
struct CvtArgs {
  const float* in[9];
  bf16* out[9];
  int cum[10];   // cumulative vec4 counts, cum[0]=0
};

__global__ void cvt_all(CvtArgs a) {
  const int total4 = a.cum[9];
  for (int i = blockIdx.x * 256 + threadIdx.x; i < total4; i += gridDim.x * 256) {
    int s = 0;
#pragma unroll 8
    while (i >= a.cum[s + 1]) ++s;        // contiguous i => wave-uniform mostly
    const int j = i - a.cum[s];
    f32x4 v = *(const f32x4*)(a.in[s] + 4 * (size_t)j);
    bf16x4 o;
#pragma unroll
    for (int k = 0; k < 4; ++k) {
      float x = v[k];
      x = (x == x) ? fminf(fmaxf(x, -65504.f), 65504.f) : 0.f;
      o[k] = (bf16)x;
    }
    *(bf16x4*)(a.out[s] + 4 * (size_t)j) = o;
  }
}

// ===========================================================================
// Round-4 changes (round-3 PMC: gemm_dual 497us, VGPR 84 with FETCH 878MB /
// WRITE 1.42GB = accumulator SCRATCH SPILLS. Cause: __launch_bounds__(256,3)
// capped VGPR ~170 while the parked-register epilogue needed ~190 live.
// 2.35GB at 4.7TB/s == the 500us. Lesson: never raise the min-occupancy
// bound past peak live regs):
//  1. gemm_dual back to __launch_bounds__(256,2); epilogue restructured into
//     4 sub-passes of 16 rows with TWO small wave-private slots (16x68 f32
//     each, 34816B total <= 48K pool) -- no register parking; LDS stays
//     49152 => 3 blocks/CU by LDS, VGPR free to land ~130 without spills.
//  2. gemm_bt (256,3)->(256,4): VGPR 76 << 128 cap; LDS 34816*4=139K<=160K
//     => 4 blocks/CU for all single GEMMs (more cross-block overlap of the
//     per-K-step vmcnt(0)+barrier drain).
// Kept: global_load_lds staging, pre-swizzled-source XOR LDS, LDS-restage
// coalesced epilogue, MODE5+6 dual fusion, concat-K C/D fusion, XCD swizzle,
// cvt_all single launch.
// MODE 0: out_bf16 = acc (+bias1 (+bias2 if K2))
// MODE 1: out_f32  = acc + extra_bf16[off]          (final residual)
// MODE 2: out_bf16 = extra_bf16[off] * silu(acc)    (z-gate)
// ===========================================================================

__device__ __forceinline__ void g2lds(const bf16* g, bf16* l) {
  __builtin_amdgcn_global_load_lds((const __attribute__((address_space(1))) void*)g,
                                   (__attribute__((address_space(3))) void*)l,
                                   16, 0, 0);
}

// One K-pass: stages [128 rows x 64 k] of A and W via global_load_lds and
// accumulates into acc. 2 barriers per K-step (m97 structure).
template<int KK>
__device__ __forceinline__ void gemm_pass(const bf16* __restrict__ Abase,
                                          const bf16* __restrict__ Wbase,
                                          bf16* lds_a, bf16* lds_b,
                                          f32x4 (&acc)[4][4],
                                          int wave, int lane,
                                          size_t arow0, size_t brow0) {
  const int wm = wave >> 1, wn = wave & 1;
  const int r_in = lane >> 3;
  const int kc_l = (lane & 7) ^ r_in;     // pre-swizzled global k-chunk
  const int mrow = lane & 15;
  const int kg   = lane >> 4;

  const bf16* pa[4];
  const bf16* pb[4];
#pragma unroll
  for (int iss = 0; iss < 4; ++iss) {
    const int row = (iss * 4 + wave) * 8 + r_in;
    pa[iss] = Abase + (arow0 + row) * (size_t)KK + kc_l * 8;
    pb[iss] = Wbase + (brow0 + row) * (size_t)KK + kc_l * 8;
  }

#pragma unroll 1
  for (int k0 = 0; k0 < KK; k0 += 64) {
    __syncthreads();                      // prev tile's readers done
#pragma unroll
    for (int iss = 0; iss < 4; ++iss) {
      const int chunk = iss * 4 + wave;   // wave-uniform LDS base; lane*16 implicit
      g2lds(pa[iss], &lds_a[chunk * 512]); pa[iss] += 64;
      g2lds(pb[iss], &lds_b[chunk * 512]); pb[iss] += 64;
    }
    __syncthreads();                      // vmcnt(0) drain => tile valid
#pragma unroll
    for (int ks = 0; ks < 2; ++ks) {
      bf16x8 af[4], bfr[4];
#pragma unroll
      for (int t = 0; t < 4; ++t) {
        const int ra = wm * 64 + t * 16 + mrow;
        const int sa = ra * 8 + ((ks * 4 + kg) ^ (ra & 7));
        af[t] = *(const bf16x8*)&lds_a[sa * 8];
        const int rb = wn * 64 + t * 16 + mrow;
        const int sb = rb * 8 + ((ks * 4 + kg) ^ (rb & 7));
        bfr[t] = *(const bf16x8*)&lds_b[sb * 8];
      }
#pragma unroll
      for (int i = 0; i < 4; ++i)
#pragma unroll
        for (int j = 0; j < 4; ++j)
          acc[i][j] = __builtin_amdgcn_mfma_f32_16x16x32_bf16(af[i], bfr[j], acc[i][j], 0, 0, 0);
    }
  }
}

template<int MODE, bool HAS_BIAS, int N, int K1, int K2>
__global__ __launch_bounds__(256, 4)
void gemm_bt(const bf16* __restrict__ A1, const bf16* __restrict__ W1,
             const float* __restrict__ bias1,
             const bf16* __restrict__ A2, const bf16* __restrict__ W2,
             const float* __restrict__ bias2,
             const void* __restrict__ extra, void* __restrict__ outp) {
  // K-loop uses [0,32768); epilogue reuses pool as 4 per-wave 32x68 f32 slots.
  __shared__ __align__(16) char pool[34816];
  bf16* lds_a = (bf16*)pool;
  bf16* lds_b = (bf16*)(pool + 16384);

  const int tid  = threadIdx.x;
  const int wave = tid >> 6;
  const int lane = tid & 63;
  const int wm = wave >> 1, wn = wave & 1;

  // XCD-aware swizzle (bijective: gridDim.y % 8 == 0).
  constexpr int NBN = N / 128;
  const int nbm8 = (int)(gridDim.y >> 3);
  const int id   = (int)(blockIdx.y * NBN + blockIdx.x);
  const int xcd  = id & 7;
  const unsigned jj = (unsigned)id >> 3;
  const int bm   = xcd * nbm8 + (int)(jj / (unsigned)NBN);
  const int bn   = (int)(jj & (NBN - 1));
  const size_t arow0 = (size_t)bm * 128;
  const size_t brow0 = (size_t)bn * 128;

  f32x4 acc[4][4];
#pragma unroll
  for (int i = 0; i < 4; ++i)
#pragma unroll
    for (int j = 0; j < 4; ++j) acc[i][j] = {0.f, 0.f, 0.f, 0.f};

  gemm_pass<K1>(A1, W1, lds_a, lds_b, acc, wave, lane, arow0, brow0);
  if constexpr (K2 > 0)
    gemm_pass<K2>(A2, W2, lds_a, lds_b, acc, wave, lane, arow0, brow0);

  const int mrow = lane & 15;
  const int kg   = lane >> 4;

  // Epilogue: LDS restage -> coalesced stores (see round-1 notes).
  __syncthreads();
  float* eps = (float*)pool + wave * 2176; // 32*68 floats per wave
  const int rr  = lane >> 3;
  const int cc  = (lane & 7) * 8;
  const int gcol0 = bn * 128 + wn * 64 + cc;
  f32x4 bv0 = {0.f, 0.f, 0.f, 0.f}, bv1 = {0.f, 0.f, 0.f, 0.f};
  if constexpr (HAS_BIAS) {
    bv0 = *(const f32x4*)(bias1 + gcol0);
    bv1 = *(const f32x4*)(bias1 + gcol0 + 4);
  }
  if constexpr (K2 > 0) {
    bv0 += *(const f32x4*)(bias2 + gcol0);
    bv1 += *(const f32x4*)(bias2 + gcol0 + 4);
  }

#pragma unroll
  for (int p = 0; p < 2; ++p) {
#pragma unroll
    for (int ii = 0; ii < 2; ++ii) {
      const int i = p * 2 + ii;
#pragma unroll
      for (int j = 0; j < 4; ++j)
#pragma unroll
        for (int r = 0; r < 4; ++r)
          eps[(ii * 16 + kg * 4 + r) * 68 + j * 16 + mrow] = acc[i][j][r];
    }
#pragma unroll
    for (int rnd = 0; rnd < 4; ++rnd) {
      const int lr   = rnd * 8 + rr;
      const int grow = bm * 128 + wm * 64 + p * 32 + lr;
      f32x4 v0 = *(const f32x4*)&eps[lr * 68 + cc];
      f32x4 v1 = *(const f32x4*)&eps[lr * 68 + cc + 4];
      const size_t off = (size_t)grow * N + gcol0;
      float vv[8];
#pragma unroll
      for (int k = 0; k < 4; ++k) { vv[k] = v0[k] + bv0[k]; vv[4 + k] = v1[k] + bv1[k]; }

      float res[8];
      if constexpr (MODE == 0) {
#pragma unroll
        for (int k = 0; k < 8; ++k) res[k] = vv[k];
      } else if constexpr (MODE == 1) {
        bf16x8 e = *(const bf16x8*)((const bf16*)extra + off);
#pragma unroll
        for (int k = 0; k < 8; ++k) res[k] = vv[k] + (float)e[k];
      } else {  // MODE 2
        bf16x8 g = *(const bf16x8*)((const bf16*)extra + off);
#pragma unroll
        for (int k = 0; k < 8; ++k) {
          const float v = vv[k];
          res[k] = (float)g[k] * (v / (1.f + __expf(-v)));
        }
      }

      if constexpr (MODE == 1) {
        f32x4 o0, o1;
#pragma unroll
        for (int k = 0; k < 4; ++k) { o0[k] = res[k]; o1[k] = res[4 + k]; }
        *(f32x4*)((float*)outp + off)     = o0;
        *(f32x4*)((float*)outp + off + 4) = o1;
      } else {
        bf16x8 o;
#pragma unroll
        for (int k = 0; k < 8; ++k) o[k] = (bf16)res[k];
        *(bf16x8*)((bf16*)outp + off) = o;
      }
    }
  }
}

// ===========================================================================
// Dual GEMM: nla = softplus(A.dlw^T + b1) * (A.Aw^T + b2). Shares the A-tile
// across two accumulators; W1/W2 each staged. N=2048, K=1024.
// LDS 49152 (3 K-loop tiles) => 3 blocks/CU by LDS. launch_bounds(256,2)
// (VGPR cap 256 -- round-3's (256,3) cap ~170 caused accumulator spills,
// 2.3GB scratch traffic). Epilogue: 4 sub-passes of 16 rows through TWO
// small wave-private slots (16x68 f32 each; 34816B total) -- no register
// parking, peak live ~= acc1+acc2+temps.
// ===========================================================================
template<int N, int K>
__global__ __launch_bounds__(256, 2)
void gemm_dual(const bf16* __restrict__ A, const bf16* __restrict__ W1,
               const bf16* __restrict__ W2, const float* __restrict__ b1,
               const float* __restrict__ b2, bf16* __restrict__ outp) {
  __shared__ __align__(16) char pool[49152];
  bf16* lds_a  = (bf16*)pool;
  bf16* lds_b1 = (bf16*)(pool + 16384);
  bf16* lds_b2 = (bf16*)(pool + 32768);

  const int tid  = threadIdx.x;
  const int wave = tid >> 6;
  const int lane = tid & 63;
  const int wm = wave >> 1, wn = wave & 1;

  constexpr int NBN = N / 128;
  const int nbm8 = (int)(gridDim.y >> 3);
  const int id   = (int)(blockIdx.y * NBN + blockIdx.x);
  const int xcd  = id & 7;
  const unsigned jj = (unsigned)id >> 3;
  const int bm   = xcd * nbm8 + (int)(jj / (unsigned)NBN);
  const int bn   = (int)(jj & (NBN - 1));
  const size_t arow0 = (size_t)bm * 128;
  const size_t brow0 = (size_t)bn * 128;

  const int r_in = lane >> 3;
  const int kc_l = (lane & 7) ^ r_in;
  const int mrow = lane & 15;
  const int kg   = lane >> 4;

  f32x4 acc1[4][4], acc2[4][4];
#pragma unroll
  for (int i = 0; i < 4; ++i)
#pragma unroll
    for (int j = 0; j < 4; ++j) { acc1[i][j] = {0.f,0.f,0.f,0.f}; acc2[i][j] = {0.f,0.f,0.f,0.f}; }

  const bf16* pa[4]; const bf16* pb1[4]; const bf16* pb2[4];
#pragma unroll
  for (int iss = 0; iss < 4; ++iss) {
    const int row = (iss * 4 + wave) * 8 + r_in;
    pa[iss]  = A  + (arow0 + row) * (size_t)K + kc_l * 8;
    pb1[iss] = W1 + (brow0 + row) * (size_t)K + kc_l * 8;
    pb2[iss] = W2 + (brow0 + row) * (size_t)K + kc_l * 8;
  }

#pragma unroll 1
  for (int k0 = 0; k0 < K; k0 += 64) {
    __syncthreads();
#pragma unroll
    for (int iss = 0; iss < 4; ++iss) {
      const int chunk = iss * 4 + wave;
      g2lds(pa[iss],  &lds_a [chunk * 512]); pa[iss]  += 64;
      g2lds(pb1[iss], &lds_b1[chunk * 512]); pb1[iss] += 64;
      g2lds(pb2[iss], &lds_b2[chunk * 512]); pb2[iss] += 64;
    }
    __syncthreads();
#pragma unroll
    for (int ks = 0; ks < 2; ++ks) {
      bf16x8 af[4], b1f[4], b2f[4];
#pragma unroll
      for (int t = 0; t < 4; ++t) {
        const int ra = wm * 64 + t * 16 + mrow;
        const int sa = ra * 8 + ((ks * 4 + kg) ^ (ra & 7));
        af[t] = *(const bf16x8*)&lds_a[sa * 8];
        const int rb = wn * 64 + t * 16 + mrow;
        const int sb = rb * 8 + ((ks * 4 + kg) ^ (rb & 7));
        b1f[t] = *(const bf16x8*)&lds_b1[sb * 8];
        b2f[t] = *(const bf16x8*)&lds_b2[sb * 8];
      }
#pragma unroll
      for (int i = 0; i < 4; ++i)
#pragma unroll
        for (int j = 0; j < 4; ++j) {
          acc1[i][j] = __builtin_amdgcn_mfma_f32_16x16x32_bf16(af[i], b1f[j], acc1[i][j], 0, 0, 0);
          acc2[i][j] = __builtin_amdgcn_mfma_f32_16x16x32_bf16(af[i], b2f[j], acc2[i][j], 0, 0, 0);
        }
    }
  }

  // Epilogue: 4 sub-passes of 16 rows; per wave two 16x68-f32 slots (8704B);
  // same-wave DS ops are program-ordered, slots are wave-private.
  __syncthreads();
  float* eps1 = (float*)pool + wave * 2176;   // 2 slots x 1088 floats
  float* eps2 = eps1 + 1088;
  const int rr  = lane >> 3;
  const int cc  = (lane & 7) * 8;
  const int gcol0 = bn * 128 + wn * 64 + cc;
  f32x4 b1v0 = *(const f32x4*)(b1 + gcol0);
  f32x4 b1v1 = *(const f32x4*)(b1 + gcol0 + 4);
  f32x4 b2v0 = *(const f32x4*)(b2 + gcol0);
  f32x4 b2v1 = *(const f32x4*)(b2 + gcol0 + 4);

#pragma unroll
  for (int i = 0; i < 4; ++i) {
#pragma unroll
    for (int j = 0; j < 4; ++j)
#pragma unroll
      for (int r = 0; r < 4; ++r) {
        const int lr = kg * 4 + r;            // 0..15
        eps1[lr * 68 + j * 16 + mrow] = acc1[i][j][r];
        eps2[lr * 68 + j * 16 + mrow] = acc2[i][j][r];
      }
#pragma unroll
    for (int rnd = 0; rnd < 2; ++rnd) {
      const int lr   = rnd * 8 + rr;          // 0..15
      const int grow = bm * 128 + wm * 64 + i * 16 + lr;
      f32x4 u0  = *(const f32x4*)&eps1[lr * 68 + cc];
      f32x4 u1  = *(const f32x4*)&eps1[lr * 68 + cc + 4];
      f32x4 w0  = *(const f32x4*)&eps2[lr * 68 + cc];
      f32x4 w1v = *(const f32x4*)&eps2[lr * 68 + cc + 4];
      const size_t off = (size_t)grow * N + gcol0;
      bf16x8 o;
#pragma unroll
      for (int k = 0; k < 8; ++k) {
        const float dv = (k < 4 ? u0[k] + b1v0[k] : u1[k - 4] + b1v1[k - 4]);
        const float av = (k < 4 ? w0[k] + b2v0[k] : w1v[k - 4] + b2v1[k - 4]);
        const float sp = (dv > 15.f) ? dv : __logf(1.f + __expf(dv));
        o[k] = (bf16)(sp * av);
      }
      *(bf16x8*)(outp + off) = o;
    }
  }
}

// ===========================================================================
// depthwise conv1d(k=3, pad=1 along L, per-batch) + bias + silu. 8 d's/thread.
// ===========================================================================
__global__ void conv_silu_kernel(const bf16* __restrict__ t1, const float* __restrict__ cw,
                                 const float* __restrict__ cb, bf16* __restrict__ xc) {
  const int gid  = blockIdx.x * 256 + threadIdx.x;
  const int dgrp = gid & (DM / 8 - 1);
  const int bl   = gid >> 7;
  const int l    = bl & (SL - 1);
  const int d0   = dgrp * 8;
  const bf16* p  = t1 + (size_t)bl * DM + d0;
  bf16x8 cc = *(const bf16x8*)p;
  bf16x8 lf, rt;
#pragma unroll
  for (int j = 0; j < 8; ++j) { lf[j] = (bf16)0.f; rt[j] = (bf16)0.f; }
  if (l > 0)      lf = *(const bf16x8*)(p - DM);
  if (l < SL - 1) rt = *(const bf16x8*)(p + DM);
  bf16x8 o;
#pragma unroll
  for (int j = 0; j < 8; ++j) {
    const int d = d0 + j;
    float y = cw[d * 3 + 0] * (float)lf[j] + cw[d * 3 + 1] * (float)cc[j]
            + cw[d * 3 + 2] * (float)rt[j] + cb[d];
    y = y / (1.f + __expf(-y));
    o[j] = (bf16)y;
  }
  *(bf16x8*)(xc + (size_t)bl * DM + d0) = o;
}

// ===========================================================================
// Parallel scan over L, 3 phases, chunked (LC=256, NC=16).
// ===========================================================================
__global__ void scan_phase1(bf16* nla_sl, const bf16* __restrict__ bx,
                            float* __restrict__ Lp_tot, float* __restrict__ T_tot) {
  const int g  = blockIdx.x * 256 + threadIdx.x;
  const int ch = g & (DH - 1);
  const int rc = g >> 11;
  const int b  = rc & (NB - 1);
  const int c  = rc >> 2;
  const int bc = b * DH + ch;
  size_t off = ((size_t)(b * SL + c * LC)) * DH + ch;
  float lp = 0.f, S = 0.f;
#pragma unroll 8
  for (int l = 0; l < LC; ++l, off += DH) {
    const float a = (float)nla_sl[off];
    const float x = (float)bx[off];
    lp += a;
    const float e = __expf(-fminf(fmaxf(lp, -80.f), 80.f));
    S = fmaf(x, e, S);
    nla_sl[off] = (bf16)S;
  }
  Lp_tot[c * (NB * DH) + bc] = lp;
  T_tot [c * (NB * DH) + bc] = S;
}

__global__ void scan_phase2(const float* __restrict__ Lp_tot, const float* __restrict__ T_tot,
                            float* __restrict__ lpoff, float* __restrict__ Soff) {
  const int bc = blockIdx.x * 256 + threadIdx.x;
  float lp = 0.f, S = 0.f;
#pragma unroll
  for (int c = 0; c < NC; ++c) {
    lpoff[c * (NB * DH) + bc] = lp;
    Soff [c * (NB * DH) + bc] = S;
    const float e = __expf(-fminf(fmaxf(lp, -80.f), 80.f));
    S  = fmaf(e, T_tot[c * (NB * DH) + bc], S);
    lp += Lp_tot[c * (NB * DH) + bc];
  }
}

__global__ void scan_phase3(const bf16* __restrict__ S_local, bf16* __restrict__ h,
                            const float* __restrict__ lpoff, const float* __restrict__ Soff) {
  const int g  = blockIdx.x * 256 + threadIdx.x;
  const int ch = g & (DH - 1);
  const int rc = g >> 11;
  const int b  = rc & (NB - 1);
  const int c  = rc >> 2;
  const int bc = b * DH + ch;
  const float lo = lpoff[c * (NB * DH) + bc];
  const float so = Soff [c * (NB * DH) + bc];
  const float es = __expf(-fminf(fmaxf(lo, -80.f), 80.f));
  size_t off = ((size_t)(b * SL + c * LC)) * DH + ch;
#pragma unroll 8
  for (int l = 0; l < LC; ++l, off += DH) {
    h[off] = (bf16)fmaf(es, (float)S_local[off], so);
  }
}

// ===========================================================================
// Workspace (max live 186 MB), offsets in MB:
//  [  0.. 24): bf16 weights (persistent)
//  [ 24.. 56): xc
//  [ 56..120): t1 [56,88) / xbf [88,120) -> bxh (Bx, then h) ; z [56,88)
//  [120..184): nla (scan in-place) -> ssm [120,152)
//  [184..186): scan totals
// ===========================================================================
extern "C" void kernel_launch(void* const* d_in, const int* in_sizes, int n_in,
                              void* d_out, int out_size, void* d_ws, size_t ws_size,
                              hipStream_t stream) {
  const float* x    = (const float*)d_in[0];
  const float* w1   = (const float*)d_in[1];
  const float* w2   = (const float*)d_in[2];
  const float* w3   = (const float*)d_in[3];
  const float* cw   = (const float*)d_in[4];
  const float* cb   = (const float*)d_in[5];
  const float* A_w  = (const float*)d_in[6];
  const float* A_b  = (const float*)d_in[7];
  const float* B_w  = (const float*)d_in[8];
  const float* B_b  = (const float*)d_in[9];
  const float* C_w  = (const float*)d_in[10];
  const float* C_b  = (const float*)d_in[11];
  const float* D_w  = (const float*)d_in[12];
  const float* D_b  = (const float*)d_in[13];
  const float* dl_w = (const float*)d_in[14];
  const float* dl_b = (const float*)d_in[15];

  const size_t MB = 1048576u;
  char* ws = (char*)d_ws;
  bf16* w1b  = (bf16*)(ws + 0*MB);
  bf16* w2b  = (bf16*)(ws + 2*MB);
  bf16* w3b  = (bf16*)(ws + 4*MB);
  bf16* Dwb  = (bf16*)(ws + 6*MB);
  bf16* Awb  = (bf16*)(ws + 8*MB);
  bf16* Bwb  = (bf16*)(ws + 12*MB);
  bf16* dlwb = (bf16*)(ws + 16*MB);
  bf16* Cwb  = (bf16*)(ws + 20*MB);
  bf16* xc   = (bf16*)(ws + 24*MB);
  bf16* t1   = (bf16*)(ws + 56*MB);
  bf16* z    = t1;
  bf16* xbf  = (bf16*)(ws + 88*MB);
  bf16* bxh  = (bf16*)(ws + 56*MB);   // 64 MB: Bx, then h (phase3 in-place)
  bf16* nla  = (bf16*)(ws + 120*MB);  // 64 MB; S_local in-place
  bf16* ssm  = (bf16*)(ws + 120*MB);  // 32 MB, after nla dies (post-scan3)
  float* Lp_tot = (float*)(ws + 184*MB);
  float* T_tot  = (float*)(ws + 184*MB + 524288u);
  float* lpoff  = (float*)(ws + 185*MB);
  float* Soff   = (float*)(ws + 185*MB + 524288u);
  float* outp = (float*)d_out;

  dim3 blk(256);
  dim3 g1(DM / 128, MT / 128);   // N=1024
  dim3 g2(DH / 128, MT / 128);   // N=2048

  // --- convert all inputs to bf16 (sanitizing), single launch ---
  {
    CvtArgs a;
    const float* ins[9]  = {x, w1, w2, w3, D_w, A_w, B_w, dl_w, C_w};
    bf16*        outs[9] = {xbf, w1b, w2b, w3b, Dwb, Awb, Bwb, dlwb, Cwb};
    const int    n4s[9]  = {MT*DM/4, DM*DM/4, DM*DM/4, DM*DM/4, DM*DM/4,
                            DH*DM/4, DH*DM/4, DH*DM/4, DM*DH/4};
    int c = 0;
    a.cum[0] = 0;
    for (int i = 0; i < 9; ++i) { a.in[i] = ins[i]; a.out[i] = outs[i]; c += n4s[i]; a.cum[i+1] = c; }
    cvt_all<<<2048, blk, 0, stream>>>(a);
  }

  // --- pipeline ---
  gemm_bt<0,false,DM,DM,0><<<g1, blk, 0, stream>>>(xbf, w1b, nullptr,
      nullptr, nullptr, nullptr, nullptr, t1);
  conv_silu_kernel<<<MT * DM / 8 / 256, blk, 0, stream>>>(t1, cw, cb, xc);
  gemm_dual<DH,DM><<<g2, blk, 0, stream>>>(xc, dlwb, Awb, dl_b, A_b, nla);
  gemm_bt<0,true ,DH,DM,0><<<g2, blk, 0, stream>>>(xc, Bwb, B_b,
      nullptr, nullptr, nullptr, nullptr, bxh);
  scan_phase1<<<MT * NC * DH / SL / 256, blk, 0, stream>>>(nla, bxh, Lp_tot, T_tot);
  scan_phase2<<<NB * DH / 256, blk, 0, stream>>>(Lp_tot, T_tot, lpoff, Soff);
  scan_phase3<<<MT * NC * DH / SL / 256, blk, 0, stream>>>(nla, bxh, lpoff, Soff);
  // ssm = C.h + D.x + C_b + D_b  (concatenated-K fused pass)
  gemm_bt<0,true ,DM,DH,DM><<<g1, blk, 0, stream>>>(bxh, Cwb, C_b,
      xc, Dwb, D_b, nullptr, ssm);
  gemm_bt<2,false,DM,DM,0><<<g1, blk, 0, stream>>>(ssm, w2b, nullptr,
      nullptr, nullptr, nullptr, ssm, z);
  gemm_bt<1,false,DM,DM,0><<<g1, blk, 0, stream>>>(z,   w3b, nullptr,
      nullptr, nullptr, nullptr, ssm, outp);
}